// Round 6
// baseline (126.259 us; speedup 1.0000x reference)
//
#include <hip/hip_runtime.h>
#include <hip/hip_bf16.h>

// Median blur 3x3 (kornia semantics) + fused mask copy.
// median commutes with monotone affine maps: 2*median((v+1)/2)-1 == median(v)
// with pad sentinel -1.0 (maps to reference's zero-pad in (v+1)/2 space).
//
// R6: 8-wide x 4-tall per thread (32 px). Per row: dword + 2x dwordx4 + dword
// = 4 vmem insts / 8 px -> 1.0 vmem insts per output px (was 1.375).
// Edge cols via clamped-address load + post-select (branch-free).
// Ring of 3 horizontally-sorted rows; v_med3/min3/max3; nt stores.

#define W 512
#define H 512
#define PLANE (W * H)                 // 262144
#define NPLANES 48                    // 16 * 3
#define IMG_ELEMS (PLANE * NPLANES)   // 12582912
#define MASK_ELEMS (PLANE * 16)       // 4194304
#define MED_BLOCKS 1536               // 12.58M px / 32 px/thread / 256
#define TOTAL_BLOCKS 2560             // 1536 med + 1024 mask, interleaved 3:2

typedef float nfloat4 __attribute__((ext_vector_type(4)));

__device__ __forceinline__ float med3(float a, float b, float c) {
    return __builtin_amdgcn_fmed3f(a, b, c);
}
__device__ __forceinline__ float min3(float a, float b, float c) {
    return fminf(fminf(a, b), c);     // -> v_min3_f32
}
__device__ __forceinline__ float max3(float a, float b, float c) {
    return fmaxf(fmaxf(a, b), c);     // -> v_max3_f32
}

__global__ __launch_bounds__(256) void fused_kernel(
        const float* __restrict__ img, const float* __restrict__ mask,
        float* __restrict__ out) {
    unsigned b = blockIdx.x;
    unsigned q = b / 5u, rsel = b % 5u;

    if (rsel >= 3u) {
        // ---- mask copy: 1024 blocks interleaved 2-per-5 ----
        int m = (int)(q * 2u + (rsel - 3u));          // 0..1023
        int i = m * 1024 + threadIdx.x;               // base float4 index
        const nfloat4* src = (const nfloat4*)mask;
        nfloat4* dst = (nfloat4*)(out + IMG_ELEMS);
        #pragma unroll
        for (int k = 0; k < 4; ++k) {
            nfloat4 v = __builtin_nontemporal_load(src + i + k * 256);
            __builtin_nontemporal_store(v, dst + i + k * 256);
        }
        return;
    }

    // ---- median path: [plane 48][rowblk 128][xseg 64] ----
    int d = (int)(q * 3u + rsel);    // 0..1535
    int idx = d * 256 + threadIdx.x;
    int xseg = idx & 63;
    int rb = (idx >> 6) & 127;
    int p = idx >> 13;               // 0..47
    int x0 = xseg << 3;              // 0..504
    int y0 = rb << 2;                // 0..508

    const float* plane = img + (size_t)p * PLANE;
    float* outp = out + (size_t)p * PLANE + y0 * W + x0;

    // Ring of 3 horizontally-sorted rows: rl/rm/rh[s][k] = sorted
    // {t[k], t[k+1], t[k+2]} (k = 0..7 over the 10-col window).
    float rl[3][8], rm[3][8], rh[3][8];

    #pragma unroll
    for (int r = 0; r < 6; ++r) {
        int yy = y0 + r - 1;
        float t[10];
        if (yy >= 0 && yy < H) {          // wave-uniform (rb uniform in wave)
            const float* row = plane + yy * W;
            // clamped-address edge loads, fixed up with selects (no exec mask)
            float tl = row[x0 > 0 ? x0 - 1 : 0];
            nfloat4 a = *(const nfloat4*)(row + x0);       // aligned
            nfloat4 c = *(const nfloat4*)(row + x0 + 4);   // aligned
            float tr = row[x0 + 8 < W ? x0 + 8 : W - 1];
            t[0] = (x0 > 0) ? tl : -1.0f;
            t[1] = a.x; t[2] = a.y; t[3] = a.z; t[4] = a.w;
            t[5] = c.x; t[6] = c.y; t[7] = c.z; t[8] = c.w;
            t[9] = (x0 + 8 < W) ? tr : -1.0f;
        } else {
            #pragma unroll
            for (int j = 0; j < 10; ++j) t[j] = -1.0f;
        }

        int s = r % 3;
        #pragma unroll
        for (int k = 0; k < 8; ++k) {
            rl[s][k] = min3(t[k], t[k + 1], t[k + 2]);
            rm[s][k] = med3(t[k], t[k + 1], t[k + 2]);
            rh[s][k] = max3(t[k], t[k + 1], t[k + 2]);
        }

        if (r >= 2) {
            int oy = r - 2;
            int s0 = oy % 3, s1 = (oy + 1) % 3, s2 = (oy + 2) % 3;
            nfloat4 o0, o1;
            #pragma unroll
            for (int k = 0; k < 8; ++k) {
                float mx = max3(rl[s0][k], rl[s1][k], rl[s2][k]);
                float md = med3(rm[s0][k], rm[s1][k], rm[s2][k]);
                float mn = min3(rh[s0][k], rh[s1][k], rh[s2][k]);
                float v = med3(mx, md, mn);
                if (k < 4) o0[k] = v; else o1[k - 4] = v;
            }
            __builtin_nontemporal_store(o0, (nfloat4*)(outp + oy * W));
            __builtin_nontemporal_store(o1, (nfloat4*)(outp + oy * W + 4));
        }
    }
}

extern "C" void kernel_launch(void* const* d_in, const int* in_sizes, int n_in,
                              void* d_out, int out_size, void* d_ws, size_t ws_size,
                              hipStream_t stream) {
    const float* img  = (const float*)d_in[0];
    const float* mask = (const float*)d_in[1];
    float* out = (float*)d_out;

    fused_kernel<<<TOTAL_BLOCKS, 256, 0, stream>>>(img, mask, out);
}

// Round 7
// 116.631 us; speedup vs baseline: 1.0825x; 1.0825x over previous
//
#include <hip/hip_runtime.h>
#include <hip/hip_bf16.h>

// Median blur 3x3 (kornia semantics) + fused mask copy.
// median commutes with monotone affine maps: 2*median((v+1)/2)-1 == median(v)
// with pad sentinel -1.0 (maps to reference's zero-pad in (v+1)/2 space).
//
// R7: LDS-staged. Block = 8 output rows x 512 cols of one plane.
//  - stage 10 input rows (20 KB LDS) via 5 coalesced dwordx4 loads/thread
//  - compute reads neighbors from LDS (no global edge gathers at all)
//  - 20 KB LDS -> 8 blocks/CU -> full 32-wave occupancy (VGPR low)
//  - no nontemporal anywhere (R6 evidence: nt stores amplified WRITE 1.5x)
//  - mask copy = tail blocks, R3's proven chunked form

#define W 512
#define H 512
#define PLANE (W * H)                 // 262144
#define NPLANES 48                    // 16 * 3
#define IMG_ELEMS (PLANE * NPLANES)   // 12582912
#define MASK_ELEMS (PLANE * 16)       // 4194304
#define MASK_F4 (MASK_ELEMS / 4)      // 1048576
#define MED_BLOCKS (NPLANES * (H / 8))        // 3072 (64 blocks/plane)
#define MASK_BLOCKS 1024
#define TOTAL_BLOCKS (MED_BLOCKS + MASK_BLOCKS)

typedef float nfloat4 __attribute__((ext_vector_type(4)));

__device__ __forceinline__ float med3(float a, float b, float c) {
    return __builtin_amdgcn_fmed3f(a, b, c);
}
__device__ __forceinline__ float min3(float a, float b, float c) {
    return fminf(fminf(a, b), c);     // -> v_min3_f32
}
__device__ __forceinline__ float max3(float a, float b, float c) {
    return fmaxf(fmaxf(a, b), c);     // -> v_max3_f32
}

__global__ __launch_bounds__(256) void fused_kernel(
        const float* __restrict__ img, const float* __restrict__ mask,
        float* __restrict__ out) {
    unsigned b = blockIdx.x;

    if (b >= MED_BLOCKS) {
        // ---- mask copy: tail blocks, 4 float4 per thread, chunk-strided ----
        int i = (int)(b - MED_BLOCKS) * 256 + threadIdx.x;   // [0, 262144)
        const nfloat4* src = (const nfloat4*)mask;
        nfloat4* dst = (nfloat4*)(out + IMG_ELEMS);
        #pragma unroll
        for (int k = 0; k < 4; ++k) {
            int j = i + k * (MASK_F4 / 4);
            dst[j] = src[j];
        }
        return;
    }

    // ---- median path: block = plane p, 8 output rows starting at w*8 ----
    int p = (int)b >> 6;          // 0..47
    int w = (int)b & 63;          // 0..63
    int ybase = w << 3;           // first output row
    const float* plane = img + (size_t)p * PLANE;

    // Stage 10 input rows [ybase-1, ybase+9) into LDS; pad rows = -1.
    __shared__ float lds[10 * W];         // 20 KB
    {
        int y0m1 = ybase - 1;
        #pragma unroll
        for (int k = 0; k < 5; ++k) {
            int i = threadIdx.x + k * 256;    // 0..1279
            int r = i >> 7;                    // 0..9
            int c = (i & 127) << 2;            // 0..508
            int yy = y0m1 + r;
            nfloat4 v;
            if (yy >= 0 && yy < H) {
                v = *(const nfloat4*)(plane + yy * W + c);
            } else {
                v = (nfloat4){-1.0f, -1.0f, -1.0f, -1.0f};
            }
            *(nfloat4*)&lds[r * W + c] = v;
        }
    }
    __syncthreads();

    // Compute: thread = (xseg 0..127, rb 0..1) -> 4 output rows x float4.
    int xseg = threadIdx.x & 127;
    int rb = threadIdx.x >> 7;
    int x0 = xseg << 2;                   // 0..508
    int lr = rb << 2;                     // local input-row base (rows lr..lr+5)
    float* outp = out + (size_t)p * PLANE + (size_t)(ybase + (rb << 2)) * W + x0;

    // Ring of 3 horizontally-sorted rows.
    float rl[3][4], rm[3][4], rh[3][4];

    #pragma unroll
    for (int r = 0; r < 6; ++r) {
        const float* row = &lds[(lr + r) * W];
        nfloat4 c = *(const nfloat4*)(row + x0);
        // clamped-address LDS reads + value select (stay in bounds)
        float tl = row[x0 > 0 ? x0 - 1 : 0];
        float tr = row[x0 + 4 < W ? x0 + 4 : W - 1];
        float t0 = (x0 > 0) ? tl : -1.0f;
        float t5 = (x0 + 4 < W) ? tr : -1.0f;
        float t1 = c.x, t2 = c.y, t3 = c.z, t4 = c.w;

        int s = r % 3;
        rl[s][0] = min3(t0, t1, t2); rm[s][0] = med3(t0, t1, t2); rh[s][0] = max3(t0, t1, t2);
        rl[s][1] = min3(t1, t2, t3); rm[s][1] = med3(t1, t2, t3); rh[s][1] = max3(t1, t2, t3);
        rl[s][2] = min3(t2, t3, t4); rm[s][2] = med3(t2, t3, t4); rh[s][2] = max3(t2, t3, t4);
        rl[s][3] = min3(t3, t4, t5); rm[s][3] = med3(t3, t4, t5); rh[s][3] = max3(t3, t4, t5);

        if (r >= 2) {
            int oy = r - 2;
            int s0 = oy % 3, s1 = (oy + 1) % 3, s2 = (oy + 2) % 3;
            nfloat4 o;
            #pragma unroll
            for (int k = 0; k < 4; ++k) {
                float mx = max3(rl[s0][k], rl[s1][k], rl[s2][k]);
                float md = med3(rm[s0][k], rm[s1][k], rm[s2][k]);
                float mn = min3(rh[s0][k], rh[s1][k], rh[s2][k]);
                o[k] = med3(mx, md, mn);
            }
            *(nfloat4*)(outp + oy * W) = o;
        }
    }
}

extern "C" void kernel_launch(void* const* d_in, const int* in_sizes, int n_in,
                              void* d_out, int out_size, void* d_ws, size_t ws_size,
                              hipStream_t stream) {
    const float* img  = (const float*)d_in[0];
    const float* mask = (const float*)d_in[1];
    float* out = (float*)d_out;

    fused_kernel<<<TOTAL_BLOCKS, 256, 0, stream>>>(img, mask, out);
}

// Round 8
// 115.910 us; speedup vs baseline: 1.0893x; 1.0062x over previous
//
#include <hip/hip_runtime.h>
#include <hip/hip_bf16.h>

// Median blur 3x3 (kornia semantics) + fused mask copy.
// median commutes with monotone affine maps: 2*median((v+1)/2)-1 == median(v)
// with pad sentinel -1.0 (maps to reference's zero-pad in (v+1)/2 space).
//
// R8 = R7 (LDS-staged, 8 rows x 512 cols per block) + mask copy fused INTO
// every med block (1/3072 slice each, issued first so it overlaps the
// staging barrier and med compute). No tail blocks -> no drain serialization.

#define W 512
#define H 512
#define PLANE (W * H)                 // 262144
#define NPLANES 48                    // 16 * 3
#define IMG_ELEMS (PLANE * NPLANES)   // 12582912
#define MASK_ELEMS (PLANE * 16)       // 4194304
#define MASK_F4 (MASK_ELEMS / 4)      // 1048576
#define MED_BLOCKS (NPLANES * (H / 8))        // 3072 (64 blocks/plane)
#define MASK_PER_BLOCK 342            // ceil(1048576 / 3072)

typedef float nfloat4 __attribute__((ext_vector_type(4)));

__device__ __forceinline__ float med3(float a, float b, float c) {
    return __builtin_amdgcn_fmed3f(a, b, c);
}
__device__ __forceinline__ float min3(float a, float b, float c) {
    return fminf(fminf(a, b), c);     // -> v_min3_f32
}
__device__ __forceinline__ float max3(float a, float b, float c) {
    return fmaxf(fmaxf(a, b), c);     // -> v_max3_f32
}

__global__ __launch_bounds__(256) void fused_kernel(
        const float* __restrict__ img, const float* __restrict__ mask,
        float* __restrict__ out) {
    int b = blockIdx.x;

    // ---- mask slice for this block: issued first, overlaps everything ----
    {
        const nfloat4* src = (const nfloat4*)mask;
        nfloat4* dst = (nfloat4*)(out + IMG_ELEMS);
        int base = b * MASK_PER_BLOCK;
        int end = base + MASK_PER_BLOCK;
        if (end > MASK_F4) end = MASK_F4;
        #pragma unroll
        for (int k = 0; k < 2; ++k) {
            int j = base + threadIdx.x + k * 256;
            if (j < end) dst[j] = src[j];
        }
    }

    // ---- median path: block = plane p, 8 output rows starting at w*8 ----
    int p = b >> 6;               // 0..47
    int w = b & 63;               // 0..63
    int ybase = w << 3;           // first output row
    const float* plane = img + (size_t)p * PLANE;

    // Stage 10 input rows [ybase-1, ybase+9) into LDS; pad rows = -1.
    __shared__ float lds[10 * W];         // 20 KB
    {
        int y0m1 = ybase - 1;
        #pragma unroll
        for (int k = 0; k < 5; ++k) {
            int i = threadIdx.x + k * 256;     // 0..1279
            int r = i >> 7;                    // 0..9
            int c = (i & 127) << 2;            // 0..508
            int yy = y0m1 + r;
            nfloat4 v;
            if (yy >= 0 && yy < H) {
                v = *(const nfloat4*)(plane + yy * W + c);
            } else {
                v = (nfloat4){-1.0f, -1.0f, -1.0f, -1.0f};
            }
            *(nfloat4*)&lds[r * W + c] = v;
        }
    }
    __syncthreads();

    // Compute: thread = (xseg 0..127, rb 0..1) -> 4 output rows x float4.
    int xseg = threadIdx.x & 127;
    int rb = threadIdx.x >> 7;
    int x0 = xseg << 2;                   // 0..508
    int lr = rb << 2;                     // local input-row base (rows lr..lr+5)
    float* outp = out + (size_t)p * PLANE + (size_t)(ybase + (rb << 2)) * W + x0;

    // Ring of 3 horizontally-sorted rows.
    float rl[3][4], rm[3][4], rh[3][4];

    #pragma unroll
    for (int r = 0; r < 6; ++r) {
        const float* row = &lds[(lr + r) * W];
        nfloat4 c = *(const nfloat4*)(row + x0);
        float tl = row[x0 > 0 ? x0 - 1 : 0];
        float tr = row[x0 + 4 < W ? x0 + 4 : W - 1];
        float t0 = (x0 > 0) ? tl : -1.0f;
        float t5 = (x0 + 4 < W) ? tr : -1.0f;
        float t1 = c.x, t2 = c.y, t3 = c.z, t4 = c.w;

        int s = r % 3;
        rl[s][0] = min3(t0, t1, t2); rm[s][0] = med3(t0, t1, t2); rh[s][0] = max3(t0, t1, t2);
        rl[s][1] = min3(t1, t2, t3); rm[s][1] = med3(t1, t2, t3); rh[s][1] = max3(t1, t2, t3);
        rl[s][2] = min3(t2, t3, t4); rm[s][2] = med3(t2, t3, t4); rh[s][2] = max3(t2, t3, t4);
        rl[s][3] = min3(t3, t4, t5); rm[s][3] = med3(t3, t4, t5); rh[s][3] = max3(t3, t4, t5);

        if (r >= 2) {
            int oy = r - 2;
            int s0 = oy % 3, s1 = (oy + 1) % 3, s2 = (oy + 2) % 3;
            nfloat4 o;
            #pragma unroll
            for (int k = 0; k < 4; ++k) {
                float mx = max3(rl[s0][k], rl[s1][k], rl[s2][k]);
                float md = med3(rm[s0][k], rm[s1][k], rm[s2][k]);
                float mn = min3(rh[s0][k], rh[s1][k], rh[s2][k]);
                o[k] = med3(mx, md, mn);
            }
            *(nfloat4*)(outp + oy * W) = o;
        }
    }
}

extern "C" void kernel_launch(void* const* d_in, const int* in_sizes, int n_in,
                              void* d_out, int out_size, void* d_ws, size_t ws_size,
                              hipStream_t stream) {
    const float* img  = (const float*)d_in[0];
    const float* mask = (const float*)d_in[1];
    float* out = (float*)d_out;

    fused_kernel<<<MED_BLOCKS, 256, 0, stream>>>(img, mask, out);
}